// Round 2
// baseline (355.895 us; speedup 1.0000x reference)
//
#include <hip/hip_runtime.h>
#include <hip/hip_bf16.h>
#include <math.h>

typedef short bf16x8 __attribute__((ext_vector_type(8)));
typedef float f32x4 __attribute__((ext_vector_type(4)));
typedef unsigned short u16;

#define AS1(p) ((const __attribute__((address_space(1))) unsigned int*)(p))
#define AS3(p) ((__attribute__((address_space(3))) unsigned int*)(p))

__device__ __forceinline__ u16 f2bf(float f) {
  union { float f; unsigned u; } v; v.f = f;
  unsigned r = v.u + 0x7fffu + ((v.u >> 16) & 1u);  // RNE
  return (u16)(r >> 16);
}

// pack 8 fp32 -> 8 bf16 by truncation (exact for 0.0/1.0 adj values)
__device__ __forceinline__ bf16x8 pack8_trunc(const float4& a, const float4& b) {
  union { float4 f; unsigned u[4]; } ua, ub; ua.f = a; ub.f = b;
  union { bf16x8 v; unsigned u[4]; } r;
  r.u[0] = (ua.u[0] >> 16) | (ua.u[1] & 0xFFFF0000u);
  r.u[1] = (ua.u[2] >> 16) | (ua.u[3] & 0xFFFF0000u);
  r.u[2] = (ub.u[0] >> 16) | (ub.u[1] & 0xFFFF0000u);
  r.u[3] = (ub.u[2] >> 16) | (ub.u[3] & 0xFFFF0000u);
  return r.v;
}

// ---------- Kernel 0: Wt[f][k] = bf16(W[k][f]) (256x256) ----------
__global__ void k_wt(const float* __restrict__ W, u16* __restrict__ Wt) {
  int idx = blockIdx.x * 256 + threadIdx.x;
#pragma unroll
  for (int q = 0; q < 4; ++q) {
    int i = idx + q * 16384;
    int f = i & 255, k = i >> 8;
    Wt[f * 256 + k] = f2bf(W[k * 256 + f]);
  }
}

// ---------- Kernel A: ht[b][f][j] = bf16( (x @ W)[b,j,f] ) ----------
// grid 512 (BM=32 rows of global M=16384), 512 threads (8 waves, 2x4 of 16x64)
__global__ __launch_bounds__(512, 4) void k_xw(
    const float* __restrict__ x, const u16* __restrict__ Wt, u16* __restrict__ ht)
{
  __shared__ u16 Ab[2][32 * 64];    // x tile  [m][k]  bf16, XOR-swizzled
  __shared__ u16 Bb[2][256 * 64];   // Wt tile [f][k]  bf16, src-pre-swizzled

  const int tid = threadIdx.x;
  const int lane = tid & 63;
  const int wid = tid >> 6;
  const int wr = wid >> 2, wc = wid & 3;

  const long row0 = (long)blockIdx.x * 32;
  const int b = (int)(row0 >> 11);
  const int jloc = (int)(row0 & 2047);
  const float* xb = x + row0 * 256;
  u16* htb = ht + ((size_t)b << 19);   // b * 256 * 2048

  const int ar = tid >> 4;             // A-stage row 0..31
  const int ac = tid & 15;             // float4 slot
  const int awb = ar * 128 + ((ac * 8) ^ ((ar & 7) << 4));

  f32x4 acc[4] = {};

  auto stage = [&](int t, int bufi) {
    const float4 v = *(const float4*)(xb + ar * 256 + t * 64 + ac * 4);
    short4 p;
    p.x = (short)f2bf(v.x); p.y = (short)f2bf(v.y);
    p.z = (short)f2bf(v.z); p.w = (short)f2bf(v.w);
    *(short4*)((char*)(&Ab[bufi][0]) + awb) = p;
#pragma unroll
    for (int q = 0; q < 4; ++q) {
      const int fbase = wid * 32 + q * 8;
      const int f = fbase + (lane >> 3);
      const char* src = (const char*)Wt + f * 512 + t * 128
                        + (((lane & 7) * 16) ^ ((f & 7) << 4));
      __builtin_amdgcn_global_load_lds(AS1(src),
          AS3((char*)(&Bb[bufi][0]) + fbase * 128), 16, 0, 0);
    }
  };

  auto compute = [&](int bufi) {
#pragma unroll
    for (int kk = 0; kk < 2; ++kk) {
      const int am = wr * 16 + (lane & 15);
      const bf16x8 a = *(const bf16x8*)((const char*)(&Ab[bufi][0])
          + am * 128 + ((kk * 64 + (lane >> 4) * 16) ^ ((am & 7) << 4)));
#pragma unroll
      for (int nf = 0; nf < 4; ++nf) {
        const int bn = wc * 64 + nf * 16 + (lane & 15);
        const bf16x8 bv = *(const bf16x8*)((const char*)(&Bb[bufi][0])
            + bn * 128 + ((kk * 64 + (lane >> 4) * 16) ^ ((bn & 7) << 4)));
        acc[nf] = __builtin_amdgcn_mfma_f32_16x16x32_bf16(a, bv, acc[nf], 0, 0, 0);
      }
    }
  };

  stage(0, 0);
  __syncthreads();
#pragma unroll 2
  for (int t = 0; t < 4; ++t) {
    const int cur = t & 1;
    if (t + 1 < 4) stage(t + 1, cur ^ 1);
    compute(cur);
    __syncthreads();
  }

  const int j0 = jloc + wr * 16 + ((lane >> 4) << 2);
#pragma unroll
  for (int nf = 0; nf < 4; ++nf) {
    const int f = wc * 64 + nf * 16 + (lane & 15);
    short4 p;
    p.x = (short)f2bf(acc[nf][0]);
    p.y = (short)f2bf(acc[nf][1]);
    p.z = (short)f2bf(acc[nf][2]);
    p.w = (short)f2bf(acc[nf][3]);
    *(short4*)(&htb[(size_t)f * 2048 + j0]) = p;
  }
}

// ---------- Kernel B: out = elu( (1/deg) * adj @ h ) ----------
// Barrier-free, LDS-free. grid 512 = 8 batches x 64 row-blocks (BM=32).
// 8 waves (2 wr x 4 wc): wave owns 16 rows x 64 f.
// A (adj, HBM) loaded straight into MFMA A-frag layout, D=2 reg prefetch.
// B (ht, L2-resident 1MB/batch) loaded straight into B-frags per use.
__global__ __launch_bounds__(512, 4) void k_agg(
    const float* __restrict__ adj, const u16* __restrict__ ht, float* __restrict__ out)
{
  const int tid = threadIdx.x;
  const int lane = tid & 63;
  const int wid = tid >> 6;
  const int wr = wid >> 2, wc = wid & 3;

  const int b = blockIdx.x & 7;       // batch -> XCD-local ht in L2
  const int rb = blockIdx.x >> 3;
  const int row0 = rb * 32;

  const int kg = lane >> 4;           // k-group 0..3 (8 elems each)
  const int mloc = lane & 15;         // A row / B col within fragment

  // A: lane reads adj[b][row0 + wr*16 + mloc][t*64 + kk*32 + kg*8 .. +8]
  const float* arow = adj + ((size_t)b * 2048 + row0 + wr * 16 + mloc) * 2048 + kg * 8;
  // B: lane reads ht[b][wc*64 + nf*16 + mloc][t*64 + kk*32 + kg*8 .. +8]
  const u16* htb = ht + ((size_t)b << 19);
  const u16* brow0 = htb + (size_t)(wc * 64 + 0 * 16 + mloc) * 2048 + kg * 8;
  const u16* brow1 = htb + (size_t)(wc * 64 + 1 * 16 + mloc) * 2048 + kg * 8;
  const u16* brow2 = htb + (size_t)(wc * 64 + 2 * 16 + mloc) * 2048 + kg * 8;
  const u16* brow3 = htb + (size_t)(wc * 64 + 3 * 16 + mloc) * 2048 + kg * 8;

  f32x4 acc[4] = {};
  float deg = 0.f;

  auto loadA = [&](int t, float4 (&A)[4]) {
    const float* p = arow + t * 64;
    A[0] = *(const float4*)(p);
    A[1] = *(const float4*)(p + 4);
    A[2] = *(const float4*)(p + 32);
    A[3] = *(const float4*)(p + 36);
  };

  auto body = [&](int t, float4 (&A)[4]) {
    // consume A (cvt + deg), then immediately issue prefetch for t+2
    const bf16x8 af0 = pack8_trunc(A[0], A[1]);
    const bf16x8 af1 = pack8_trunc(A[2], A[3]);
    deg += A[0].x + A[0].y + A[0].z + A[0].w
         + A[1].x + A[1].y + A[1].z + A[1].w
         + A[2].x + A[2].y + A[2].z + A[2].w
         + A[3].x + A[3].y + A[3].z + A[3].w;
    int tn = t + 2; if (tn > 31) tn = 31;   // clamped, never consumed past end
    loadA(tn, A);

    const int off0 = t * 64;
    {
      bf16x8 b0 = *(const bf16x8*)(brow0 + off0);
      bf16x8 b1 = *(const bf16x8*)(brow1 + off0);
      bf16x8 b2 = *(const bf16x8*)(brow2 + off0);
      bf16x8 b3 = *(const bf16x8*)(brow3 + off0);
      acc[0] = __builtin_amdgcn_mfma_f32_16x16x32_bf16(af0, b0, acc[0], 0, 0, 0);
      acc[1] = __builtin_amdgcn_mfma_f32_16x16x32_bf16(af0, b1, acc[1], 0, 0, 0);
      acc[2] = __builtin_amdgcn_mfma_f32_16x16x32_bf16(af0, b2, acc[2], 0, 0, 0);
      acc[3] = __builtin_amdgcn_mfma_f32_16x16x32_bf16(af0, b3, acc[3], 0, 0, 0);
    }
    {
      const int off1 = off0 + 32;
      bf16x8 b0 = *(const bf16x8*)(brow0 + off1);
      bf16x8 b1 = *(const bf16x8*)(brow1 + off1);
      bf16x8 b2 = *(const bf16x8*)(brow2 + off1);
      bf16x8 b3 = *(const bf16x8*)(brow3 + off1);
      acc[0] = __builtin_amdgcn_mfma_f32_16x16x32_bf16(af1, b0, acc[0], 0, 0, 0);
      acc[1] = __builtin_amdgcn_mfma_f32_16x16x32_bf16(af1, b1, acc[1], 0, 0, 0);
      acc[2] = __builtin_amdgcn_mfma_f32_16x16x32_bf16(af1, b2, acc[2], 0, 0, 0);
      acc[3] = __builtin_amdgcn_mfma_f32_16x16x32_bf16(af1, b3, acc[3], 0, 0, 0);
    }
  };

  float4 A0[4], A1[4];
  loadA(0, A0);
  loadA(1, A1);
  for (int t = 0; t < 32; t += 2) {
    body(t, A0);
    body(t + 1, A1);
  }

  // deg: lanes {m, m+16, m+32, m+48} hold partial sums of row m
  deg += __shfl_xor(deg, 16);
  deg += __shfl_xor(deg, 32);

  // epilogue: C/D row = (lane>>4)*4 + r, col = lane&15
  const int r0 = (lane >> 4) << 2;
  float* outb = out + ((size_t)b * 2048 + row0 + wr * 16) * 256;
  float sc[4];
#pragma unroll
  for (int r = 0; r < 4; ++r) {
    const float d = __shfl(deg, r0 + r);
    sc[r] = d > 0.f ? 1.f / d : (1.f / 2048.f);
  }
#pragma unroll
  for (int nf = 0; nf < 4; ++nf) {
    const int f = wc * 64 + nf * 16 + mloc;
#pragma unroll
    for (int r = 0; r < 4; ++r) {
      const float v = acc[nf][r] * sc[r];
      outb[(size_t)(r0 + r) * 256 + f] = v > 0.f ? v : expm1f(v);
    }
  }
}

extern "C" void kernel_launch(void* const* d_in, const int* in_sizes, int n_in,
                              void* d_out, int out_size, void* d_ws, size_t ws_size,
                              hipStream_t stream) {
  const float* x   = (const float*)d_in[0];
  const float* adj = (const float*)d_in[1];
  const float* W   = (const float*)d_in[2];
  // d_in[3] ('a') is mathematically dead: softmax rows are constant over the
  // active (adj>0) entries, so attention = 1/deg regardless of e.
  float* out = (float*)d_out;

  u16* Wt = (u16*)d_ws;                          // 256*256*2   = 128 KB
  u16* ht = (u16*)((char*)d_ws + (131072));      // 8*256*2048*2 = 8 MB

  k_wt<<<64, 256, 0, stream>>>(W, Wt);
  k_xw<<<512, 512, 0, stream>>>(x, Wt, ht);
  k_agg<<<512, 512, 0, stream>>>(adj, ht, out);
}

// Round 3
// 58.975 us; speedup vs baseline: 6.0347x; 6.0347x over previous
//
#include <hip/hip_runtime.h>
#include <hip/hip_bf16.h>
#include <math.h>

typedef short bf16x8 __attribute__((ext_vector_type(8)));
typedef float f32x4 __attribute__((ext_vector_type(4)));
typedef unsigned short u16;

#define AS1(p) ((const __attribute__((address_space(1))) unsigned int*)(p))
#define AS3(p) ((__attribute__((address_space(3))) unsigned int*)(p))

// raw sync primitives: memory-clobber asm so no memory op crosses a phase edge
#define WAITVM5 asm volatile("s_waitcnt vmcnt(5)" ::: "memory")
#define WAITVM0 asm volatile("s_waitcnt vmcnt(0)" ::: "memory")
#define LGKM0   asm volatile("s_waitcnt lgkmcnt(0)" ::: "memory")
#define BARRIER asm volatile("s_barrier" ::: "memory")

__device__ __forceinline__ u16 f2bf(float f) {
  union { float f; unsigned u; } v; v.f = f;
  unsigned r = v.u + 0x7fffu + ((v.u >> 16) & 1u);  // RNE
  return (u16)(r >> 16);
}

// ---------- Kernel 0: Wt[f][k] = bf16(W[k][f]) (256x256) ----------
__global__ void k_wt(const float* __restrict__ W, u16* __restrict__ Wt) {
  int idx = blockIdx.x * 256 + threadIdx.x;
#pragma unroll
  for (int q = 0; q < 4; ++q) {
    int i = idx + q * 16384;
    int f = i & 255, k = i >> 8;
    Wt[f * 256 + k] = f2bf(W[k * 256 + f]);
  }
}

// ---------- Kernel A: ht[b][f][j] = bf16( (x @ W)[b,j,f] ) ----------
__global__ __launch_bounds__(512, 4) void k_xw(
    const float* __restrict__ x, const u16* __restrict__ Wt, u16* __restrict__ ht)
{
  __shared__ u16 Ab[2][32 * 64];
  __shared__ u16 Bb[2][256 * 64];

  const int tid = threadIdx.x;
  const int lane = tid & 63;
  const int wid = tid >> 6;
  const int wr = wid >> 2, wc = wid & 3;

  const long row0 = (long)blockIdx.x * 32;
  const int b = (int)(row0 >> 11);
  const int jloc = (int)(row0 & 2047);
  const float* xb = x + row0 * 256;
  u16* htb = ht + ((size_t)b << 19);

  const int ar = tid >> 4;
  const int ac = tid & 15;
  const int awb = ar * 128 + ((ac * 8) ^ ((ar & 7) << 4));

  f32x4 acc[4] = {};

  auto stage = [&](int t, int bufi) {
    const float4 v = *(const float4*)(xb + ar * 256 + t * 64 + ac * 4);
    short4 p;
    p.x = (short)f2bf(v.x); p.y = (short)f2bf(v.y);
    p.z = (short)f2bf(v.z); p.w = (short)f2bf(v.w);
    *(short4*)((char*)(&Ab[bufi][0]) + awb) = p;
#pragma unroll
    for (int q = 0; q < 4; ++q) {
      const int fbase = wid * 32 + q * 8;
      const int f = fbase + (lane >> 3);
      const char* src = (const char*)Wt + f * 512 + t * 128
                        + (((lane & 7) * 16) ^ ((f & 7) << 4));
      __builtin_amdgcn_global_load_lds(AS1(src),
          AS3((char*)(&Bb[bufi][0]) + fbase * 128), 16, 0, 0);
    }
  };

  auto compute = [&](int bufi) {
#pragma unroll
    for (int kk = 0; kk < 2; ++kk) {
      const int am = wr * 16 + (lane & 15);
      const bf16x8 a = *(const bf16x8*)((const char*)(&Ab[bufi][0])
          + am * 128 + ((kk * 64 + (lane >> 4) * 16) ^ ((am & 7) << 4)));
#pragma unroll
      for (int nf = 0; nf < 4; ++nf) {
        const int bn = wc * 64 + nf * 16 + (lane & 15);
        const bf16x8 bv = *(const bf16x8*)((const char*)(&Bb[bufi][0])
            + bn * 128 + ((kk * 64 + (lane >> 4) * 16) ^ ((bn & 7) << 4)));
        acc[nf] = __builtin_amdgcn_mfma_f32_16x16x32_bf16(a, bv, acc[nf], 0, 0, 0);
      }
    }
  };

  stage(0, 0);
  __syncthreads();
#pragma unroll 2
  for (int t = 0; t < 4; ++t) {
    const int cur = t & 1;
    if (t + 1 < 4) stage(t + 1, cur ^ 1);
    compute(cur);
    __syncthreads();
  }

  const int j0 = jloc + wr * 16 + ((lane >> 4) << 2);
#pragma unroll
  for (int nf = 0; nf < 4; ++nf) {
    const int f = wc * 64 + nf * 16 + (lane & 15);
    short4 p;
    p.x = (short)f2bf(acc[nf][0]);
    p.y = (short)f2bf(acc[nf][1]);
    p.z = (short)f2bf(acc[nf][2]);
    p.w = (short)f2bf(acc[nf][3]);
    *(short4*)(&htb[(size_t)f * 2048 + j0]) = p;
  }
}

// ---------- Kernel B: out = elu( (1/deg) * adj @ h ) ----------
// Round-1 structure + counted-vmcnt pipeline (T4) + async A split (T14).
// Per stage(): exactly 5 VMEM ops/thread (1 adj float4 + 4 global_load_lds).
// Main loop never drains vmcnt to 0: wait vmcnt(5) = tile t done, t+1 in flight.
__global__ __launch_bounds__(512, 4) void k_agg(
    const float* __restrict__ adj, const u16* __restrict__ ht, float* __restrict__ out)
{
  __shared__ u16 Ab[2][32 * 64];    // adj tile [i][j] bf16, XOR-swizzled
  __shared__ u16 Bb[2][256 * 64];   // ht tile  [f][j] bf16, src-pre-swizzled

  const int tid = threadIdx.x;
  const int lane = tid & 63;
  const int wid = tid >> 6;
  const int wr = wid >> 2, wc = wid & 3;

  const int b = blockIdx.x & 7;     // batch -> XCD-local ht in L2
  const int rb = blockIdx.x >> 3;
  const int row0 = rb * 32;

  const float* adjb = adj + ((size_t)b * 2048 + row0) * 2048;
  const u16* htb = ht + ((size_t)b << 19);
  float* outb = out + ((size_t)b * 2048 + row0) * 256;

  const int ar = tid >> 4;
  const int ac = tid & 15;
  const int awb = ar * 128 + ((ac * 8) ^ ((ar & 7) << 4));

  float deg = 0.f;
  f32x4 acc[4] = {};
  float4 rA0, rA1;                  // A reg-split double buffer (static names)

  // issue tile t's loads: adj -> regs, ht -> LDS (pre-swizzled source)
  auto stage = [&](int t, float4& rA) {
    rA = *(const float4*)(adjb + (size_t)ar * 2048 + t * 64 + ac * 4);
#pragma unroll
    for (int q = 0; q < 4; ++q) {
      const int fbase = wid * 32 + q * 8;
      const int f = fbase + (lane >> 3);
      const char* src = (const char*)htb + (size_t)f * 4096 + t * 128
                        + (((lane & 7) * 16) ^ ((f & 7) << 4));
      __builtin_amdgcn_global_load_lds(AS1(src),
          AS3((char*)(&Bb[t & 1][0]) + fbase * 128), 16, 0, 0);
    }
  };

  // consume A regs: deg + cvt + swizzled ds_write
  auto writeA = [&](int bufi, float4& rA) {
    deg += rA.x + rA.y + rA.z + rA.w;       // adj is 0/1 -> exact rowsum
    short4 p;
    p.x = (short)f2bf(rA.x); p.y = (short)f2bf(rA.y);
    p.z = (short)f2bf(rA.z); p.w = (short)f2bf(rA.w);
    *(short4*)((char*)(&Ab[bufi][0]) + awb) = p;
  };

  auto compute = [&](int bufi) {
#pragma unroll
    for (int kk = 0; kk < 2; ++kk) {
      const int am = wr * 16 + (lane & 15);
      const bf16x8 a = *(const bf16x8*)((const char*)(&Ab[bufi][0])
          + am * 128 + ((kk * 64 + (lane >> 4) * 16) ^ ((am & 7) << 4)));
#pragma unroll
      for (int nf = 0; nf < 4; ++nf) {
        const int bn = wc * 64 + nf * 16 + (lane & 15);
        const bf16x8 bv = *(const bf16x8*)((const char*)(&Bb[bufi][0])
            + bn * 128 + ((kk * 64 + (lane >> 4) * 16) ^ ((bn & 7) << 4)));
        acc[nf] = __builtin_amdgcn_mfma_f32_16x16x32_bf16(a, bv, acc[nf], 0, 0, 0);
      }
    }
  };

  stage(0, rA0);                    // 5 VMEM in flight
  stage(1, rA1);                    // 10 in flight
#pragma unroll 2
  for (int t = 0; t < 31; ++t) {
    const int cur = t & 1;
    WAITVM5;                        // oldest 5 = tile t landed; t+1 in flight
    writeA(cur, cur ? rA1 : rA0);   // cvt+ds_write adj tile t
    LGKM0;                          // ds_write visible before barrier
    BARRIER;
    compute(cur);
    LGKM0;                          // all LDS reads retired
    BARRIER;                        // buffer t&1 free for reuse
    if (t < 30) stage(t + 2, cur ? rA1 : rA0);  // refill: 5 more in flight
  }
  // t = 31: only its own 5 loads outstanding
  WAITVM0;
  writeA(1, rA1);
  LGKM0;
  BARRIER;
  compute(1);

  // deg: reduce across the 16 threads (ac) that loaded row `ar`
#pragma unroll
  for (int s = 1; s < 16; s <<= 1) deg += __shfl_xor(deg, s);
  float* degLds = (float*)&Ab[0][0];     // Ab[0] dead now (last read: t=30)
  if ((tid & 15) == 0) degLds[ar] = deg;
  __syncthreads();

  const int j0 = wr * 16 + ((lane >> 4) << 2);
  float sc[4];
#pragma unroll
  for (int r = 0; r < 4; ++r) {
    const float d = degLds[j0 + r];
    sc[r] = d > 0.f ? 1.f / d : (1.f / 2048.f);
  }
#pragma unroll
  for (int nf = 0; nf < 4; ++nf) {
    const int f = wc * 64 + nf * 16 + (lane & 15);
#pragma unroll
    for (int r = 0; r < 4; ++r) {
      const float v = acc[nf][r] * sc[r];
      outb[(size_t)(j0 + r) * 256 + f] = v > 0.f ? v : expm1f(v);
    }
  }
}

extern "C" void kernel_launch(void* const* d_in, const int* in_sizes, int n_in,
                              void* d_out, int out_size, void* d_ws, size_t ws_size,
                              hipStream_t stream) {
  const float* x   = (const float*)d_in[0];
  const float* adj = (const float*)d_in[1];
  const float* W   = (const float*)d_in[2];
  // d_in[3] ('a') is mathematically dead: softmax rows are constant over the
  // active (adj>0) entries, so attention = 1/deg regardless of e.
  float* out = (float*)d_out;

  u16* Wt = (u16*)d_ws;                          // 256*256*2   = 128 KB
  u16* ht = (u16*)((char*)d_ws + (131072));      // 8*256*2048*2 = 8 MB

  k_wt<<<64, 256, 0, stream>>>(W, Wt);
  k_xw<<<512, 512, 0, stream>>>(x, Wt, ht);
  k_agg<<<512, 512, 0, stream>>>(adj, ht, out);
}